// Round 1
// baseline (131.889 us; speedup 1.0000x reference)
//
#include <hip/hip_runtime.h>

#define N_NODES 50000
#define K_DEG   17
#define DIN     128
#define DOUT    64
#define NPW     8      // nodes per wave in median (R13)

typedef _Float16 f16;
typedef __attribute__((ext_vector_type(8))) short  short8;   // bf16 A/B frag (4 VGPR)
typedef __attribute__((ext_vector_type(4))) float  floatx4;  // C/D frag

// ---------------------------------------------------------------------------
// Batcher merge-exchange sorting network (compile-time; fully unrolls).
// ---------------------------------------------------------------------------
struct CEPair { unsigned char a, b; };

constexpr int net_count(int n) {
  int t = 0; while ((1 << t) < n) ++t;
  int cnt = 0;
  for (int p = 1 << (t - 1); p > 0; p >>= 1) {
    int q = 1 << (t - 1), r = 0, d = p;
    for (;;) {
      for (int i = 0; i < n - d; ++i)
        if ((i & p) == r) ++cnt;
      if (q == p) break;
      d = q - p; q >>= 1; r = p;
    }
  }
  return cnt;
}

template <int NP> struct NetArr { CEPair v[NP]; };

template <int NP>
constexpr NetArr<NP> net_pairs(int n) {
  NetArr<NP> out{};
  int t = 0; while ((1 << t) < n) ++t;
  int cnt = 0;
  for (int p = 1 << (t - 1); p > 0; p >>= 1) {
    int q = 1 << (t - 1), r = 0, d = p;
    for (;;) {
      for (int i = 0; i < n - d; ++i)
        if ((i & p) == r) {
          out.v[cnt].a = (unsigned char)i;
          out.v[cnt].b = (unsigned char)(i + d);
          ++cnt;
        }
      if (q == p) break;
      d = q - p; q >>= 1; r = p;
    }
  }
  return out;
}

constexpr int NP17 = net_count(K_DEG);   // 74 compare-exchanges for n=17

// ---------------------------------------------------------------------------
// bf16 helpers (RNE)
// ---------------------------------------------------------------------------
__device__ __forceinline__ unsigned int f2bf(float f) {
  union { float f; unsigned int u; } c; c.f = f;
  return (c.u + 0x7FFFu + ((c.u >> 16) & 1u)) >> 16;
}
__device__ __forceinline__ float bf2f(unsigned int b) {
  union { float f; unsigned int u; } c; c.u = b << 16;
  return c.f;
}

// ---------------------------------------------------------------------------
// Kernel 0: convert W -> frag-ordered bf16 hi/lo table T (32 KB). Frozen.
// ---------------------------------------------------------------------------
__global__ void convw_kernel(const float* __restrict__ W,
                             unsigned short* __restrict__ T) {
  const int flat = blockIdx.x * 256 + threadIdx.x;   // 0..8191
  const int j    = flat & 7;
  const int lane = (flat >> 3) & 63;
  const int pair = flat >> 9;                        // 0..15
  const int ks   = pair >> 2, nt = pair & 3;
  const int k    = ks * 32 + (lane >> 4) * 8 + j;
  const int n    = nt * 16 + (lane & 15);
  const float f  = W[k * DOUT + n];
  const unsigned int hb = f2bf(f);
  const float        lo = f - bf2f(hb);
  const unsigned int lb = f2bf(lo);
  T[flat]        = (unsigned short)hb;
  T[flat + 8192] = (unsigned short)lb;
}

// ---------------------------------------------------------------------------
// Kernel 1: xp = x @ W via bf16 MFMA, 3-term hi/lo split; fp16 output.
// Frozen since R4/R8 (near its memory floor).
// ---------------------------------------------------------------------------
__global__ __launch_bounds__(256) void gemm_kernel(
    const float* __restrict__ x, const unsigned short* __restrict__ T,
    f16* __restrict__ xp) {
  const int gwave = blockIdx.x * 4 + (threadIdx.x >> 6);
  if (gwave >= (N_NODES / 16)) return;
  const int lane = threadIdx.x & 63;
  const int r0 = gwave * 16;
  const int m  = lane & 15;     // A row within tile
  const int q  = lane >> 4;     // k-quad

  const float4* x4 = (const float4*)x;
  float4 xr[8];
  #pragma unroll
  for (int ks = 0; ks < 4; ++ks) {
    const int base = (r0 + m) * (DIN / 4) + ks * 8 + q * 2;
    xr[ks * 2 + 0] = x4[base + 0];
    xr[ks * 2 + 1] = x4[base + 1];
  }

  floatx4 acc[4];
  #pragma unroll
  for (int nt = 0; nt < 4; ++nt) acc[nt] = (floatx4){0.f, 0.f, 0.f, 0.f};

  const short8* Th = (const short8*)T;
  const short8* Tl = (const short8*)(T + 8192);

  #pragma unroll
  for (int ks = 0; ks < 4; ++ks) {
    short8 Bh[4], Bl[4];
    #pragma unroll
    for (int nt = 0; nt < 4; ++nt) {
      const int fi = (ks * 4 + nt) * 64 + lane;
      Bh[nt] = Th[fi];
      Bl[nt] = Tl[fi];
    }
    float f[8] = {xr[ks*2].x, xr[ks*2].y, xr[ks*2].z, xr[ks*2].w,
                  xr[ks*2+1].x, xr[ks*2+1].y, xr[ks*2+1].z, xr[ks*2+1].w};
    union { unsigned int i[4]; short8 s; } Ah, Al;
    #pragma unroll
    for (int r = 0; r < 4; ++r) {
      const unsigned int h0 = f2bf(f[2*r]),   h1 = f2bf(f[2*r+1]);
      const unsigned int l0 = f2bf(f[2*r]   - bf2f(h0));
      const unsigned int l1 = f2bf(f[2*r+1] - bf2f(h1));
      Ah.i[r] = h0 | (h1 << 16);
      Al.i[r] = l0 | (l1 << 16);
    }
    #pragma unroll
    for (int nt = 0; nt < 4; ++nt) {
      acc[nt] = __builtin_amdgcn_mfma_f32_16x16x32_bf16(Al.s, Bh[nt], acc[nt], 0, 0, 0);
      acc[nt] = __builtin_amdgcn_mfma_f32_16x16x32_bf16(Ah.s, Bl[nt], acc[nt], 0, 0, 0);
      acc[nt] = __builtin_amdgcn_mfma_f32_16x16x32_bf16(Ah.s, Bh[nt], acc[nt], 0, 0, 0);
    }
  }

  #pragma unroll
  for (int nt = 0; nt < 4; ++nt) {
    const int col = nt * 16 + m;
    #pragma unroll
    for (int r = 0; r < 4; ++r)
      xp[(r0 + q * 4 + r) * DOUT + col] = (f16)acc[nt][r];
  }
}

// ---------------------------------------------------------------------------
// Kernel 2: weighted per-dim median + scale + bias.
// R13: back to 256-thr blocks (R10 best-measured config), but each wave now
// owns NPW=8 consecutive nodes with an explicit 2-deep software pipeline:
// node i+1's col s_loads + 17 gathers + w LDS write (double-buffered 128B
// slot) are issued BEFORE node i's sort/cumsum/store. Theory: median was
// latency/turnover-bound (55% occupancy with no static limiter; 1-node
// waves pay the full s_load->gather serial chain ~1500cy for ~500cy of
// issue). In-wave pipelining hides the next node's memory latency under
// the current node's 74-CE sort, independent of occupancy.
// Arithmetic is bit-identical to R10/R12: min/max sort, j*4 packed into the
// 13 zero LSBs of fp16-sourced fp32 (exact), one-copy-per-node w broadcast,
// cumsum sequential in sorted order, total = last cum, scale by total.
// ---------------------------------------------------------------------------
__global__ __launch_bounds__(256) void median_kernel(
    const f16* __restrict__ xp, const int* __restrict__ col,
    const float* __restrict__ ew, const float* __restrict__ bias,
    float* __restrict__ out) {
  __shared__ float wlds[4 * 2 * 32];     // [wave][buf][32 floats] = 256B/wave

  const int wave = threadIdx.x >> 6;
  const int lane = threadIdx.x & 63;
  // first node of this wave's run; wave-uniform by construction
  const int wbase = __builtin_amdgcn_readfirstlane((blockIdx.x * 4 + wave) * NPW);

  const float bl = bias[lane];
  float* wl = wlds + wave * 64;          // two 32-float buffers

  constexpr NetArr<NP17> NET = net_pairs<NP17>(K_DEG);

  float vcur[K_DEG];

  // ---- prologue: issue loads for node wbase (parity buffer 0)
  if (wbase < N_NODES) {
    const int*   cp = col + wbase * K_DEG;   // uniform -> s_load
    const float* wp = ew  + wbase * K_DEG;   // uniform
    int c[K_DEG];
    #pragma unroll
    for (int j = 0; j < K_DEG; ++j) c[j] = cp[j];
    #pragma unroll
    for (int j = 0; j < K_DEG; ++j)
      vcur[j] = (float)xp[c[j] * DOUT + lane];   // 128B coalesced fp16 gather
    if (lane < K_DEG) wl[lane] = wp[lane];
  }

  #pragma unroll
  for (int i = 0; i < NPW; ++i) {
    const int node = wbase + i;
    float vnxt[K_DEG];

    // ---- prefetch node i+1 into parity buffer (i+1)&1 (no barrier needed:
    // per-wave private LDS slots, program-order DS ops)
    if (i + 1 < NPW && node + 1 < N_NODES) {
      const int*   cp = col + (node + 1) * K_DEG;
      const float* wp = ew  + (node + 1) * K_DEG;
      int c[K_DEG];
      #pragma unroll
      for (int j = 0; j < K_DEG; ++j) c[j] = cp[j];
      #pragma unroll
      for (int j = 0; j < K_DEG; ++j)
        vnxt[j] = (float)xp[c[j] * DOUT + lane];
      if (lane < K_DEG) wl[((i + 1) & 1) * 32 + lane] = wp[lane];
    }

    // ---- process node i out of registers (hides the prefetch latency)
    if (node < N_NODES) {
      // pack j*4 into mantissa LSBs (exact: fp16->fp32 leaves 13 zero LSBs;
      // j*4 <= 64 fits bits [2..6]); extraction mask 0x7C as byte offset
      float v[K_DEG];
      #pragma unroll
      for (int j = 0; j < K_DEG; ++j) {
        union { float f; unsigned int u; } c2; c2.f = vcur[j];
        c2.u |= (unsigned)(j * 4);
        v[j] = c2.f;
      }

      // sort ascending — min/max-only compile-time Batcher network
      #pragma unroll
      for (int s = 0; s < NP17; ++s) {
        const int a = NET.v[s].a, b = NET.v[s].b;
        const float va = v[a], vb = v[b];
        v[a] = fminf(va, vb);
        v[b] = fmaxf(va, vb);
      }

      // recover w in sorted order (broadcast LDS read) + exact-order cumsum
      const unsigned base = (unsigned)(wave * 256 + (i & 1) * 128); // 128B-aligned
      const char* wbytes = (const char*)wlds;
      float run = 0.f, cum[K_DEG];
      #pragma unroll
      for (int j = 0; j < K_DEG; ++j) {
        union { float f; unsigned int u; } c2; c2.f = v[j];
        const float swj = *(const float*)(wbytes + ((c2.u & 0x7Cu) | base));
        run += swj; cum[j] = run;            // exact reference cumsum order
      }
      const float half = 0.5f * run;         // run == total == cum[-1]

      // first sorted position with cum >= half: backward cndmask scan
      float med = v[K_DEG - 1];
      #pragma unroll
      for (int j = K_DEG - 2; j >= 0; --j)
        med = (cum[j] >= half) ? v[j] : med;

      out[node * DOUT + lane] = run * med + bl;
    }

    // rotate pipeline registers (SSA under full unroll -> no real movs)
    #pragma unroll
    for (int j = 0; j < K_DEG; ++j) vcur[j] = vnxt[j];
  }
}

// ---------------------------------------------------------------------------
extern "C" void kernel_launch(void* const* d_in, const int* in_sizes, int n_in,
                              void* d_out, int out_size, void* d_ws, size_t ws_size,
                              hipStream_t stream) {
  const float* x    = (const float*)d_in[0];
  const int*   ei   = (const int*)d_in[1];
  const float* ew   = (const float*)d_in[2];
  const float* W    = (const float*)d_in[3];
  const float* bias = (const float*)d_in[4];
  float*       out  = (float*)d_out;

  f16*            xp = (f16*)d_ws;                              // 6.4 MB
  unsigned short* T  = (unsigned short*)((char*)d_ws + (size_t)N_NODES * DOUT * 2);
  const int*      colp = ei + (size_t)N_NODES * K_DEG;          // edge_index[1]

  convw_kernel<<<8192 / 256, 256, 0, stream>>>(W, T);
  gemm_kernel<<<(N_NODES / 16 + 3) / 4, 256, 0, stream>>>(x, T, xp);
  median_kernel<<<(N_NODES + 4 * NPW - 1) / (4 * NPW), 256, 0, stream>>>(
      xp, colp, ew, bias, out);
}

// Round 2
// 120.352 us; speedup vs baseline: 1.0959x; 1.0959x over previous
//
#include <hip/hip_runtime.h>

#define N_NODES 50000
#define K_DEG   17
#define DIN     128
#define DOUT    64
#define NPW     4      // nodes per wave in median (R14: batched, not pipelined)

typedef _Float16 f16;
typedef __attribute__((ext_vector_type(8))) short  short8;   // bf16 A/B frag (4 VGPR)
typedef __attribute__((ext_vector_type(4))) float  floatx4;  // C/D frag

// ---------------------------------------------------------------------------
// Batcher merge-exchange sorting network (compile-time; fully unrolls).
// ---------------------------------------------------------------------------
struct CEPair { unsigned char a, b; };

constexpr int net_count(int n) {
  int t = 0; while ((1 << t) < n) ++t;
  int cnt = 0;
  for (int p = 1 << (t - 1); p > 0; p >>= 1) {
    int q = 1 << (t - 1), r = 0, d = p;
    for (;;) {
      for (int i = 0; i < n - d; ++i)
        if ((i & p) == r) ++cnt;
      if (q == p) break;
      d = q - p; q >>= 1; r = p;
    }
  }
  return cnt;
}

template <int NP> struct NetArr { CEPair v[NP]; };

template <int NP>
constexpr NetArr<NP> net_pairs(int n) {
  NetArr<NP> out{};
  int t = 0; while ((1 << t) < n) ++t;
  int cnt = 0;
  for (int p = 1 << (t - 1); p > 0; p >>= 1) {
    int q = 1 << (t - 1), r = 0, d = p;
    for (;;) {
      for (int i = 0; i < n - d; ++i)
        if ((i & p) == r) {
          out.v[cnt].a = (unsigned char)i;
          out.v[cnt].b = (unsigned char)(i + d);
          ++cnt;
        }
      if (q == p) break;
      d = q - p; q >>= 1; r = p;
    }
  }
  return out;
}

constexpr int NP17 = net_count(K_DEG);   // 74 compare-exchanges for n=17

// ---------------------------------------------------------------------------
// bf16 helpers (RNE)
// ---------------------------------------------------------------------------
__device__ __forceinline__ unsigned int f2bf(float f) {
  union { float f; unsigned int u; } c; c.f = f;
  return (c.u + 0x7FFFu + ((c.u >> 16) & 1u)) >> 16;
}
__device__ __forceinline__ float bf2f(unsigned int b) {
  union { float f; unsigned int u; } c; c.u = b << 16;
  return c.f;
}

// ---------------------------------------------------------------------------
// Kernel 0: convert W -> frag-ordered bf16 hi/lo table T (32 KB). Frozen.
// ---------------------------------------------------------------------------
__global__ void convw_kernel(const float* __restrict__ W,
                             unsigned short* __restrict__ T) {
  const int flat = blockIdx.x * 256 + threadIdx.x;   // 0..8191
  const int j    = flat & 7;
  const int lane = (flat >> 3) & 63;
  const int pair = flat >> 9;                        // 0..15
  const int ks   = pair >> 2, nt = pair & 3;
  const int k    = ks * 32 + (lane >> 4) * 8 + j;
  const int n    = nt * 16 + (lane & 15);
  const float f  = W[k * DOUT + n];
  const unsigned int hb = f2bf(f);
  const float        lo = f - bf2f(hb);
  const unsigned int lb = f2bf(lo);
  T[flat]        = (unsigned short)hb;
  T[flat + 8192] = (unsigned short)lb;
}

// ---------------------------------------------------------------------------
// Kernel 1: xp = x @ W via bf16 MFMA, 3-term hi/lo split; fp16 output.
// Frozen since R4/R8 (near its memory floor).
// ---------------------------------------------------------------------------
__global__ __launch_bounds__(256) void gemm_kernel(
    const float* __restrict__ x, const unsigned short* __restrict__ T,
    f16* __restrict__ xp) {
  const int gwave = blockIdx.x * 4 + (threadIdx.x >> 6);
  if (gwave >= (N_NODES / 16)) return;
  const int lane = threadIdx.x & 63;
  const int r0 = gwave * 16;
  const int m  = lane & 15;     // A row within tile
  const int q  = lane >> 4;     // k-quad

  const float4* x4 = (const float4*)x;
  float4 xr[8];
  #pragma unroll
  for (int ks = 0; ks < 4; ++ks) {
    const int base = (r0 + m) * (DIN / 4) + ks * 8 + q * 2;
    xr[ks * 2 + 0] = x4[base + 0];
    xr[ks * 2 + 1] = x4[base + 1];
  }

  floatx4 acc[4];
  #pragma unroll
  for (int nt = 0; nt < 4; ++nt) acc[nt] = (floatx4){0.f, 0.f, 0.f, 0.f};

  const short8* Th = (const short8*)T;
  const short8* Tl = (const short8*)(T + 8192);

  #pragma unroll
  for (int ks = 0; ks < 4; ++ks) {
    short8 Bh[4], Bl[4];
    #pragma unroll
    for (int nt = 0; nt < 4; ++nt) {
      const int fi = (ks * 4 + nt) * 64 + lane;
      Bh[nt] = Th[fi];
      Bl[nt] = Tl[fi];
    }
    float f[8] = {xr[ks*2].x, xr[ks*2].y, xr[ks*2].z, xr[ks*2].w,
                  xr[ks*2+1].x, xr[ks*2+1].y, xr[ks*2+1].z, xr[ks*2+1].w};
    union { unsigned int i[4]; short8 s; } Ah, Al;
    #pragma unroll
    for (int r = 0; r < 4; ++r) {
      const unsigned int h0 = f2bf(f[2*r]),   h1 = f2bf(f[2*r+1]);
      const unsigned int l0 = f2bf(f[2*r]   - bf2f(h0));
      const unsigned int l1 = f2bf(f[2*r+1] - bf2f(h1));
      Ah.i[r] = h0 | (h1 << 16);
      Al.i[r] = l0 | (l1 << 16);
    }
    #pragma unroll
    for (int nt = 0; nt < 4; ++nt) {
      acc[nt] = __builtin_amdgcn_mfma_f32_16x16x32_bf16(Al.s, Bh[nt], acc[nt], 0, 0, 0);
      acc[nt] = __builtin_amdgcn_mfma_f32_16x16x32_bf16(Ah.s, Bl[nt], acc[nt], 0, 0, 0);
      acc[nt] = __builtin_amdgcn_mfma_f32_16x16x32_bf16(Ah.s, Bh[nt], acc[nt], 0, 0, 0);
    }
  }

  #pragma unroll
  for (int nt = 0; nt < 4; ++nt) {
    const int col = nt * 16 + m;
    #pragma unroll
    for (int r = 0; r < 4; ++r)
      xp[(r0 + q * 4 + r) * DOUT + col] = (f16)acc[nt][r];
  }
}

// ---------------------------------------------------------------------------
// Kernel 2: weighted per-dim median + scale + bias.
// R14: phase-separated batch of NPW=4 nodes per wave (pipeline from R13
// removed — post-mortem: its conditional prefetch + register rotation grew
// VGPR and the prefetch s_loads shared lgkmcnt with cumsum ds_reads,
// serializing the "hidden" latency into compute; occupancy fell to 27%).
// Here: ALL col s_loads for 4 nodes -> ALL 68 xp gathers (one vmcnt drain,
// 68-deep MLP) -> ALL ew->LDS -> then 4 pure-VALU sort/cumsum/store bodies.
// SMEM and DS never in flight together; zero conditionals (50000%16==0);
// all array indices compile-time (no rotation). Arithmetic bit-identical
// to R10/R12: min/max sort, j*4 packed into the 13 zero LSBs of
// fp16-sourced fp32 (exact), one-copy-per-node w broadcast via 128B-aligned
// LDS slot, cumsum sequential in sorted order, total = last cum, scale by
// total.
// ---------------------------------------------------------------------------
__global__ __launch_bounds__(256, 4) void median_kernel(
    const f16* __restrict__ xp, const int* __restrict__ col,
    const float* __restrict__ ew, const float* __restrict__ bias,
    float* __restrict__ out) {
  __shared__ float wlds[4 * NPW * 32];       // [wave][node_i][32] = 2 KB

  const int wave = threadIdx.x >> 6;
  const int lane = threadIdx.x & 63;
  // first node of this wave's batch; wave-uniform by construction
  const int wbase = __builtin_amdgcn_readfirstlane((blockIdx.x * 4 + wave) * NPW);

  const float bl = bias[lane];

  // ---- phase 1: neighbor ids for all NPW nodes (uniform -> s_loads)
  int c[NPW][K_DEG];
  #pragma unroll
  for (int i = 0; i < NPW; ++i) {
    const int* cp = col + (wbase + i) * K_DEG;
    #pragma unroll
    for (int j = 0; j < K_DEG; ++j) c[i][j] = cp[j];
  }

  // ---- phase 2: all 68 gathers issued together (128B coalesced fp16 rows)
  f16 raw[NPW][K_DEG];
  #pragma unroll
  for (int i = 0; i < NPW; ++i)
    #pragma unroll
    for (int j = 0; j < K_DEG; ++j)
      raw[i][j] = xp[c[i][j] * DOUT + lane];

  // ---- phase 3: edge weights -> per-node 128B-aligned LDS slots
  #pragma unroll
  for (int i = 0; i < NPW; ++i) {
    if (lane < K_DEG)
      wlds[(wave * NPW + i) * 32 + lane] = ew[(wbase + i) * K_DEG + lane];
  }

  constexpr NetArr<NP17> NET = net_pairs<NP17>(K_DEG);
  const char* wbytes = (const char*)wlds;

  // ---- phase 4: per-node pure-VALU body (sort/cumsum/scan/store)
  #pragma unroll
  for (int i = 0; i < NPW; ++i) {
    const int node = wbase + i;

    // convert + pack j*4 into mantissa LSBs (exact: fp16->fp32 leaves 13
    // zero LSBs; j*4 <= 64 fits bits [2..6]); extraction mask 0x7C
    float v[K_DEG];
    #pragma unroll
    for (int j = 0; j < K_DEG; ++j) {
      union { float f; unsigned int u; } c2; c2.f = (float)raw[i][j];
      c2.u |= (unsigned)(j * 4);
      v[j] = c2.f;
    }

    // sort ascending — min/max-only compile-time Batcher network
    #pragma unroll
    for (int s = 0; s < NP17; ++s) {
      const int a = NET.v[s].a, b = NET.v[s].b;
      const float va = v[a], vb = v[b];
      v[a] = fminf(va, vb);
      v[b] = fmaxf(va, vb);
    }

    // recover w in sorted order (broadcast LDS read, conflict-free) + cumsum
    const unsigned base = (unsigned)((wave * NPW + i) * 128); // 128B-aligned
    float run = 0.f, cum[K_DEG];
    #pragma unroll
    for (int j = 0; j < K_DEG; ++j) {
      union { float f; unsigned int u; } c2; c2.f = v[j];
      const float swj = *(const float*)(wbytes + ((c2.u & 0x7Cu) | base));
      run += swj; cum[j] = run;              // exact reference cumsum order
    }
    const float half = 0.5f * run;           // run == total == cum[-1]

    // first sorted position with cum >= half: backward cndmask scan
    float med = v[K_DEG - 1];
    #pragma unroll
    for (int j = K_DEG - 2; j >= 0; --j)
      med = (cum[j] >= half) ? v[j] : med;

    // scale by total (== row_sum up to ~1 ulp)
    out[node * DOUT + lane] = run * med + bl;
  }
}

// ---------------------------------------------------------------------------
extern "C" void kernel_launch(void* const* d_in, const int* in_sizes, int n_in,
                              void* d_out, int out_size, void* d_ws, size_t ws_size,
                              hipStream_t stream) {
  const float* x    = (const float*)d_in[0];
  const int*   ei   = (const int*)d_in[1];
  const float* ew   = (const float*)d_in[2];
  const float* W    = (const float*)d_in[3];
  const float* bias = (const float*)d_in[4];
  float*       out  = (float*)d_out;

  f16*            xp = (f16*)d_ws;                              // 6.4 MB
  unsigned short* T  = (unsigned short*)((char*)d_ws + (size_t)N_NODES * DOUT * 2);
  const int*      colp = ei + (size_t)N_NODES * K_DEG;          // edge_index[1]

  convw_kernel<<<8192 / 256, 256, 0, stream>>>(W, T);
  gemm_kernel<<<(N_NODES / 16 + 3) / 4, 256, 0, stream>>>(x, T, xp);
  median_kernel<<<N_NODES / (4 * NPW), 256, 0, stream>>>(xp, colp, ew, bias, out);
}